// Round 6
// baseline (367.491 us; speedup 1.0000x reference)
//
#include <hip/hip_runtime.h>
#include <math.h>
#include <float.h>

#define BATCH 128
#define LEN   100000
#define BPR   40                 // blocks per row
#define CHUNK (LEN / BPR)        // 2500 elements per block
#define VPS   (CHUNK / 4)        // 625 float4 vectors per block
#define T     512                // threads per block (8 waves)
#define TAILV (VPS - T)          // 113 vectors in group 1
#define NSEG  (BATCH * BPR)      // 5120 table entries

// ---------- workspace layout ----------
struct WS {
    int*   lt_tab; int* ht_tab; int* lp_tab; int* hp_tab;   // [NSEG]
    float* bce_blk; float* sm_blk;                          // [NSEG]
    float* cmin; float* cmax;                               // [NSEG]
    float* amp;                                             // [BATCH]
    unsigned* tick;                                         // [BATCH+1]: per-row tickets + global done
};

static inline WS ws_layout(void* d_ws) {
    WS w;
    w.lt_tab  = (int*)d_ws;
    w.ht_tab  = w.lt_tab + NSEG;
    w.lp_tab  = w.ht_tab + NSEG;
    w.hp_tab  = w.lp_tab + NSEG;
    w.bce_blk = (float*)(w.hp_tab + NSEG);
    w.sm_blk  = w.bce_blk + NSEG;
    w.cmin    = w.sm_blk  + NSEG;
    w.cmax    = w.cmin    + NSEG;
    w.amp     = w.cmax    + NSEG;
    w.tick    = (unsigned*)(w.amp + BATCH);
    return w;
}

// ---------- single fused kernel ----------
// Phase 1 (all 5120 blocks): round-4 main pass verbatim, CHUNK=2500.
//   5120 blocks / 1024 resident = exactly 5 generations -> no quantization.
// Phase 2 (last block of each row, via row ticket): window min/max scan for
//   both windows, per-row amp term. Overlaps with remaining phase-1 blocks.
// Phase 3 (last row-finisher, via global ticket): deterministic final sums.
// Round-5's launch_bounds(T,8) / stripe machinery (the 72MB write anomaly)
// is NOT carried over.

__global__ __launch_bounds__(T) void k_fused(
        const float* __restrict__ sig,
        const float* __restrict__ pred,
        const float* __restrict__ targ,
        int* __restrict__ lt_tab, int* __restrict__ ht_tab,
        int* __restrict__ lp_tab, int* __restrict__ hp_tab,
        float* __restrict__ bce_blk, float* __restrict__ sm_blk,
        float* __restrict__ cmin_tab, float* __restrict__ cmax_tab,
        float* __restrict__ amp, unsigned* __restrict__ tick,
        float* __restrict__ out) {
    const int b   = blockIdx.y;
    const int blk = blockIdx.x;          // 0..BPR-1
    const int tid = threadIdx.x;
    const size_t row = (size_t)b * LEN;
    const float* prow = pred + row;
    const float* trow = targ + row;
    const float* srow = sig  + row;
    const int base = blk * CHUNK;
    const int w = tid >> 6, lane = tid & 63;

    __shared__ float s_bce[8], s_sm[8], s_mn[8], s_mx[8];
    __shared__ int   s_lt[8], s_ht[8], s_lp[8], s_hp[8];
    __shared__ int   s_flag;
    __shared__ int   s_lo, s_hi;
    __shared__ float s_resmn[2], s_resmx[2];

    // ================= phase 1: main pass (round-4 structure) =================
    float bce = 0.0f, sm = 0.0f;
    float cmn = FLT_MAX, cmx = -FLT_MAX;
    unsigned tmask = 0u, pmask = 0u;

    #pragma unroll
    for (int k = 0; k < 2; ++k) {
        const bool act = (k == 0) || (tid < TAILV);
        if (act) {
            const int l0 = base + (tid + k * T) * 4;
            const float4 p4 = *reinterpret_cast<const float4*>(prow + l0);
            const float4 t4 = *reinterpret_cast<const float4*>(trow + l0);
            const float4 s4 = *reinterpret_cast<const float4*>(srow + l0);
            float sg0, sg1, sg2, sg3;
            #define ONE_ELEM(pp, tt, ss, sgv, BIT) { \
                const float ap = fabsf(pp); \
                const float ee = __expf(-ap); \
                const float zz = 1.0f + ee; \
                const float rr = __builtin_amdgcn_rcpf(zz); \
                bce += fmaxf(pp, 0.0f) - (pp) * (tt) + __logf(zz); \
                sgv = ((pp) >= 0.0f) ? rr : ee * rr; \
                tmask |= ((tt) > 0.5f) ? (1u << (BIT)) : 0u; \
                pmask |= ((pp) > 0.0f) ? (1u << (BIT)) : 0u; \
                cmn = fminf(cmn, (ss)); cmx = fmaxf(cmx, (ss)); }
            ONE_ELEM(p4.x, t4.x, s4.x, sg0, 4 * k + 0)
            ONE_ELEM(p4.y, t4.y, s4.y, sg1, 4 * k + 1)
            ONE_ELEM(p4.z, t4.z, s4.z, sg2, 4 * k + 2)
            ONE_ELEM(p4.w, t4.w, s4.w, sg3, 4 * k + 3)
            #undef ONE_ELEM
            sm += fabsf(sg1 - sg0) + fabsf(sg2 - sg1) + fabsf(sg3 - sg2);
            const float prev3 = __shfl_up(sg3, 1);   // lane-1's sg3
            if (lane == 0) {
                if (l0 > 0) {                        // wave boundary: recompute
                    const float pp = prow[l0 - 1];
                    const float ee = __expf(-fabsf(pp));
                    const float rr = __builtin_amdgcn_rcpf(1.0f + ee);
                    const float sp = (pp >= 0.0f) ? rr : ee * rr;
                    sm += fabsf(sg0 - sp);
                }
            } else {
                sm += fabsf(sg0 - prev3);
            }
        }
    }

    // decode index masks (bit position monotone in element index)
    int lt = LEN, ht = -1, lp = LEN, hp = -1;
    if (tmask) {
        const int f = __ffs(tmask) - 1;
        const int h = 31 - __clz((int)tmask);
        lt = base + (tid + (f >> 2) * T) * 4 + (f & 3);
        ht = base + (tid + (h >> 2) * T) * 4 + (h & 3);
    }
    if (pmask) {
        const int f = __ffs(pmask) - 1;
        const int h = 31 - __clz((int)pmask);
        lp = base + (tid + (f >> 2) * T) * 4 + (f & 3);
        hp = base + (tid + (h >> 2) * T) * 4 + (h & 3);
    }

    // block-wide reductions
    #pragma unroll
    for (int o = 32; o > 0; o >>= 1) {
        bce += __shfl_xor(bce, o);
        sm  += __shfl_xor(sm,  o);
        cmn  = fminf(cmn, __shfl_xor(cmn, o));
        cmx  = fmaxf(cmx, __shfl_xor(cmx, o));
        lt   = min(lt, __shfl_xor(lt, o));
        ht   = max(ht, __shfl_xor(ht, o));
        lp   = min(lp, __shfl_xor(lp, o));
        hp   = max(hp, __shfl_xor(hp, o));
    }
    if (lane == 0) {
        s_bce[w] = bce; s_sm[w] = sm; s_mn[w] = cmn; s_mx[w] = cmx;
        s_lt[w] = lt; s_ht[w] = ht; s_lp[w] = lp; s_hp[w] = hp;
    }
    __syncthreads();

    const int e = b * BPR + blk;
    if (tid == 0) {
        float B = 0.0f, S = 0.0f, MN = FLT_MAX, MX = -FLT_MAX;
        int LT = LEN, HT = -1, LP = LEN, HP = -1;
        #pragma unroll
        for (int i = 0; i < 8; ++i) {
            B += s_bce[i]; S += s_sm[i];
            MN = fminf(MN, s_mn[i]); MX = fmaxf(MX, s_mx[i]);
            LT = min(LT, s_lt[i]); HT = max(HT, s_ht[i]);
            LP = min(LP, s_lp[i]); HP = max(HP, s_hp[i]);
        }
        bce_blk[e] = B; sm_blk[e] = S;
        cmin_tab[e] = MN; cmax_tab[e] = MX;
        lt_tab[e] = LT; ht_tab[e] = HT;
        lp_tab[e] = LP; hp_tab[e] = HP;
        __threadfence();                               // publish tables
        const unsigned old = atomicAdd(&tick[b], 1u);  // row ticket
        s_flag = (old == BPR - 1);
    }
    __syncthreads();
    if (!s_flag) return;

    // ================= phase 2: row finisher (1 block per row) ================
    __threadfence();   // acquire: all 40 blocks' tables visible

    for (int which = 0; which < 2; ++which) {
        const int* lo_tab = which ? lp_tab : lt_tab;
        const int* hi_tab = which ? hp_tab : ht_tab;
        int lo = LEN, hi = -1;
        if (tid < BPR) { lo = lo_tab[b * BPR + tid]; hi = hi_tab[b * BPR + tid]; }
        #pragma unroll
        for (int o = 32; o > 0; o >>= 1) {
            lo = min(lo, __shfl_xor(lo, o));
            hi = max(hi, __shfl_xor(hi, o));
        }
        if (tid == 0) { s_lo = lo; s_hi = hi; }
        __syncthreads();
        lo = s_lo; hi = s_hi;

        float mn = FLT_MAX, mx = -FLT_MAX;
        if (lo < LEN) {
            const int cl = lo / CHUNK, ch = hi / CHUNK;
            const int e1 = (cl == ch) ? hi : cl * CHUNK + CHUNK - 1;
            for (int l = lo + tid; l <= e1; l += T) {
                const float x = srow[l]; mn = fminf(mn, x); mx = fmaxf(mx, x);
            }
            if (ch > cl) {
                for (int l = ch * CHUNK + tid; l <= hi; l += T) {
                    const float x = srow[l]; mn = fminf(mn, x); mx = fmaxf(mx, x);
                }
                const float* cmin_row = cmin_tab + b * BPR;
                const float* cmax_row = cmax_tab + b * BPR;
                for (int c = cl + 1 + tid; c < ch; c += T) {
                    mn = fminf(mn, cmin_row[c]); mx = fmaxf(mx, cmax_row[c]);
                }
            }
        }
        #pragma unroll
        for (int o = 32; o > 0; o >>= 1) {
            mn = fminf(mn, __shfl_xor(mn, o));
            mx = fmaxf(mx, __shfl_xor(mx, o));
        }
        if (lane == 0) { s_mn[w] = mn; s_mx[w] = mx; }
        __syncthreads();
        if (tid == 0) {
            float MN = FLT_MAX, MX = -FLT_MAX;
            #pragma unroll
            for (int i = 0; i < 8; ++i) {
                MN = fminf(MN, s_mn[i]); MX = fmaxf(MX, s_mx[i]);
            }
            if (lo >= LEN) { MN = 1e30f; MX = -1e30f; }   // invalid: MX < MN
            s_resmn[which] = MN; s_resmx[which] = MX;
        }
        __syncthreads();
    }

    if (tid == 0) {
        const float tmn = s_resmn[0], tmx = s_resmx[0];
        const float pmn = s_resmn[1], pmx = s_resmx[1];
        float a = 0.0f;
        if (tmx >= tmn && pmx >= pmn) {      // both windows valid
            const float ta = tmx - tmn;
            const float pa = pmx - pmn;
            const float d  = fabsf(ta - pa);
            a = (ta > 1e-6f) ? d / (ta + 1e-6f) : d;
        }
        amp[b] = a;
        __threadfence();                                    // publish amp
        const unsigned o2 = atomicAdd(&tick[BATCH], 1u);    // global ticket
        s_flag = (o2 == BATCH - 1);
    }
    __syncthreads();
    if (!s_flag) return;

    // ================= phase 3: final combine (1 block) =======================
    __threadfence();   // acquire: all rows' amp + all tables visible
    float acc_b = 0.0f, acc_s = 0.0f, acc_a = 0.0f;
    for (int i = tid; i < NSEG; i += T) { acc_b += bce_blk[i]; acc_s += sm_blk[i]; }
    if (tid < BATCH) acc_a = amp[tid];
    #pragma unroll
    for (int o = 32; o > 0; o >>= 1) {
        acc_b += __shfl_xor(acc_b, o);
        acc_s += __shfl_xor(acc_s, o);
        acc_a += __shfl_xor(acc_a, o);
    }
    if (lane == 0) { s_bce[w] = acc_b; s_sm[w] = acc_s; s_mn[w] = acc_a; }
    __syncthreads();
    if (tid == 0) {
        double B = 0.0, S = 0.0, A = 0.0;
        #pragma unroll
        for (int i = 0; i < 8; ++i) {
            B += (double)s_bce[i]; S += (double)s_sm[i]; A += (double)s_mn[i];
        }
        const double bced = B / ((double)BATCH * (double)LEN);
        const double smod = S / ((double)BATCH * (double)(LEN - 1));
        const double ampd = A / (double)BATCH;
        out[0] = (float)(1.0 * bced + 0.5 * ampd + 0.3 * smod);
    }
}

// ---------- launch ----------

extern "C" void kernel_launch(void* const* d_in, const int* in_sizes, int n_in,
                              void* d_out, int out_size, void* d_ws, size_t ws_size,
                              hipStream_t stream) {
    const float* signals = (const float*)d_in[0];   // (B, 1, L)
    const float* preds   = (const float*)d_in[1];   // (B, L, 1)
    const float* targs   = (const float*)d_in[2];   // (B, L, 1)
    float* out = (float*)d_out;
    WS w = ws_layout(d_ws);

    // zero the completion tickets (BATCH row tickets + 1 global)
    hipMemsetAsync(w.tick, 0, sizeof(unsigned) * (BATCH + 1), stream);

    dim3 g(BPR, BATCH);   // 5120 blocks = exactly 5 resident generations
    k_fused<<<g, T, 0, stream>>>(signals, preds, targs,
                                 w.lt_tab, w.ht_tab, w.lp_tab, w.hp_tab,
                                 w.bce_blk, w.sm_blk, w.cmin, w.cmax,
                                 w.amp, w.tick, out);
}

// Round 7
// 45.928 us; speedup vs baseline: 8.0015x; 8.0015x over previous
//
#include <hip/hip_runtime.h>
#include <math.h>
#include <float.h>

#define BATCH 128
#define LEN   100000
#define BPR   4                  // blocks per row
#define CHUNK (LEN / BPR)        // 25000 elements per block
#define VPS   (CHUNK / 4)        // 6250 float4 vectors per block
#define T     1024               // threads per block (16 waves)
#define NFULL 6                  // full groups of T vectors
#define TAILV (VPS - NFULL * T)  // 106 vectors in tail group
#define NG    (NFULL + 1)        // 7 groups
#define NST   NG                 // stripes per block (one per group)
#define STRE  (T * 4)            // 4096 elems per full stripe
#define TAILE (TAILV * 4)        // 424 elems in tail stripe
#define NSEG  (BATCH * BPR)      // 512 block-level table entries
#define NSTR  (NSEG * NST)       // 3584 stripe-level entries

// ---------- workspace layout ----------
struct WS {
    int*   lt_tab; int* ht_tab; int* lp_tab; int* hp_tab;   // [NSEG]
    float* bce_blk; float* sm_blk;                          // [NSEG]
    float* cmin; float* cmax;                               // [NSTR]
    float* wmn; float* wmx;                                 // [2*BATCH]
};

static inline WS ws_layout(void* d_ws) {
    WS w;
    w.lt_tab  = (int*)d_ws;
    w.ht_tab  = w.lt_tab + NSEG;
    w.lp_tab  = w.ht_tab + NSEG;
    w.hp_tab  = w.lp_tab + NSEG;
    w.bce_blk = (float*)(w.hp_tab + NSEG);
    w.sm_blk  = w.bce_blk + NSEG;
    w.cmin    = w.sm_blk  + NSEG;
    w.cmax    = w.cmin    + NSTR;
    w.wmn     = w.cmax    + NSTR;
    w.wmx     = w.wmn     + 2 * BATCH;
    return w;
}

// ---------- main fused pass ----------
// R6's fences reverted (device-scope fence per block = 10x slowdown).
// Geometry: 512 blocks x 1024 threads = 8192 waves = EXACTLY one resident
// generation (2 blocks/CU x 256 CU), uniform blocks -> zero dispatch
// quantization (R4's 2.5-generation grid wasted ~17%).
// Signal min/max recorded per 4096-elem stripe so k_rows' boundary scan
// stays small despite 25000-elem chunks. No launch_bounds min-waves cap
// (R5's spill cause), no fences (R6's serializer).

__global__ __launch_bounds__(T) void k_main(
        const float* __restrict__ sig,
        const float* __restrict__ pred,
        const float* __restrict__ targ,
        int* __restrict__ lt_tab, int* __restrict__ ht_tab,
        int* __restrict__ lp_tab, int* __restrict__ hp_tab,
        float* __restrict__ bce_blk, float* __restrict__ sm_blk,
        float* __restrict__ cmin_tab, float* __restrict__ cmax_tab) {
    const int b   = blockIdx.y;
    const int blk = blockIdx.x;          // 0..BPR-1
    const int tid = threadIdx.x;
    const size_t row = (size_t)b * LEN;
    const float* prow = pred + row;
    const float* trow = targ + row;
    const float* srow = sig  + row;
    const int base = blk * CHUNK;
    const int w = tid >> 6, lane = tid & 63;

    __shared__ float s_stmn[16][NST], s_stmx[16][NST];
    __shared__ float s_bce[16], s_sm[16];
    __shared__ int   s_lt[16], s_ht[16], s_lp[16], s_hp[16];

    float bce = 0.0f, sm = 0.0f;
    unsigned tmask = 0u, pmask = 0u;     // 28 bits used (7 groups x 4)

    #pragma unroll
    for (int k = 0; k < NG; ++k) {
        const bool act = (k < NFULL) || (tid < TAILV);
        float gmn = FLT_MAX, gmx = -FLT_MAX;     // per-stripe min/max
        if (act) {
            const int l0 = base + (tid + k * T) * 4;
            const float4 p4 = *reinterpret_cast<const float4*>(prow + l0);
            const float4 t4 = *reinterpret_cast<const float4*>(trow + l0);
            const float4 s4 = *reinterpret_cast<const float4*>(srow + l0);
            float sg0, sg1, sg2, sg3;
            #define ONE_ELEM(pp, tt, ss, sgv, BIT) { \
                const float ap = fabsf(pp); \
                const float ee = __expf(-ap); \
                const float zz = 1.0f + ee; \
                const float rr = __builtin_amdgcn_rcpf(zz); \
                bce += fmaxf(pp, 0.0f) - (pp) * (tt) + __logf(zz); \
                sgv = ((pp) >= 0.0f) ? rr : ee * rr; \
                tmask |= ((tt) > 0.5f) ? (1u << (BIT)) : 0u; \
                pmask |= ((pp) > 0.0f) ? (1u << (BIT)) : 0u; \
                gmn = fminf(gmn, (ss)); gmx = fmaxf(gmx, (ss)); }
            ONE_ELEM(p4.x, t4.x, s4.x, sg0, 4 * k + 0)
            ONE_ELEM(p4.y, t4.y, s4.y, sg1, 4 * k + 1)
            ONE_ELEM(p4.z, t4.z, s4.z, sg2, 4 * k + 2)
            ONE_ELEM(p4.w, t4.w, s4.w, sg3, 4 * k + 3)
            #undef ONE_ELEM
            sm += fabsf(sg1 - sg0) + fabsf(sg2 - sg1) + fabsf(sg3 - sg2);
            const float prev3 = __shfl_up(sg3, 1);   // lane-1's sg3
            if (lane == 0) {
                if (l0 > 0) {                        // wave boundary: recompute
                    const float pp = prow[l0 - 1];
                    const float ee = __expf(-fabsf(pp));
                    const float rr = __builtin_amdgcn_rcpf(1.0f + ee);
                    const float sp = (pp >= 0.0f) ? rr : ee * rr;
                    sm += fabsf(sg0 - sp);
                }
            } else {
                sm += fabsf(sg0 - prev3);
            }
        }
        // wave-reduce the stripe min/max (inactive lanes hold identity)
        #pragma unroll
        for (int o = 32; o > 0; o >>= 1) {
            gmn = fminf(gmn, __shfl_xor(gmn, o));
            gmx = fmaxf(gmx, __shfl_xor(gmx, o));
        }
        if (lane == 0) { s_stmn[w][k] = gmn; s_stmx[w][k] = gmx; }
    }

    // ---- decode index masks (bit position monotone in element index) ----
    int lt = LEN, ht = -1, lp = LEN, hp = -1;
    if (tmask) {
        const int f = __ffs(tmask) - 1;
        const int h = 31 - __clz((int)tmask);
        lt = base + (tid + (f >> 2) * T) * 4 + (f & 3);
        ht = base + (tid + (h >> 2) * T) * 4 + (h & 3);
    }
    if (pmask) {
        const int f = __ffs(pmask) - 1;
        const int h = 31 - __clz((int)pmask);
        lp = base + (tid + (f >> 2) * T) * 4 + (f & 3);
        hp = base + (tid + (h >> 2) * T) * 4 + (h & 3);
    }

    // ---- block-wide wave reductions ----
    #pragma unroll
    for (int o = 32; o > 0; o >>= 1) {
        bce += __shfl_xor(bce, o);
        sm  += __shfl_xor(sm,  o);
        lt   = min(lt, __shfl_xor(lt, o));
        ht   = max(ht, __shfl_xor(ht, o));
        lp   = min(lp, __shfl_xor(lp, o));
        hp   = max(hp, __shfl_xor(hp, o));
    }
    if (lane == 0) {
        s_bce[w] = bce; s_sm[w] = sm;
        s_lt[w] = lt; s_ht[w] = ht; s_lp[w] = lp; s_hp[w] = hp;
    }
    __syncthreads();

    const int e = b * BPR + blk;
    if (tid == 0) {
        float B = 0.0f, S = 0.0f;
        int LT = LEN, HT = -1, LP = LEN, HP = -1;
        #pragma unroll
        for (int i = 0; i < 16; ++i) {
            B += s_bce[i]; S += s_sm[i];
            LT = min(LT, s_lt[i]); HT = max(HT, s_ht[i]);
            LP = min(LP, s_lp[i]); HP = max(HP, s_hp[i]);
        }
        bce_blk[e] = B; sm_blk[e] = S;
        lt_tab[e] = LT; ht_tab[e] = HT;
        lp_tab[e] = LP; hp_tab[e] = HP;
    }
    if (tid < NST) {
        float mn = s_stmn[0][tid], mx = s_stmx[0][tid];
        #pragma unroll
        for (int i = 1; i < 16; ++i) {
            mn = fminf(mn, s_stmn[i][tid]); mx = fmaxf(mx, s_stmx[i][tid]);
        }
        cmin_tab[e * NST + tid] = mn;
        cmax_tab[e * NST + tid] = mx;
    }
}

// ---------- windowed min/max per (row, which) ----------

__device__ __forceinline__ int stripe_of(int l) {
    const int bk = l / CHUNK;
    int st = (l - bk * CHUNK) >> 12;     // /4096, max 6
    return bk * NST + st;
}
__device__ __forceinline__ int stripe_start(int sid) {
    const int bk = sid / NST, st = sid - bk * NST;
    return bk * CHUNK + st * STRE;
}
__device__ __forceinline__ int stripe_end(int sid) {     // inclusive
    const int bk = sid / NST, st = sid - bk * NST;
    return bk * CHUNK + st * STRE + ((st < NST - 1) ? STRE : TAILE) - 1;
}

__global__ __launch_bounds__(512) void k_rows(
        const float* __restrict__ sig,
        const int* __restrict__ lt_tab, const int* __restrict__ ht_tab,
        const int* __restrict__ lp_tab, const int* __restrict__ hp_tab,
        const float* __restrict__ cmin_tab, const float* __restrict__ cmax_tab,
        float* __restrict__ wmn, float* __restrict__ wmx) {
    const int b     = blockIdx.x;
    const int which = blockIdx.y;          // 0 = target window, 1 = pred window
    const int tid   = threadIdx.x;
    const int* lo_tab = which ? lp_tab : lt_tab;
    const int* hi_tab = which ? hp_tab : ht_tab;

    int lo = LEN, hi = -1;
    if (tid < BPR) { lo = lo_tab[b * BPR + tid]; hi = hi_tab[b * BPR + tid]; }
    #pragma unroll
    for (int o = 32; o > 0; o >>= 1) {
        lo = min(lo, __shfl_xor(lo, o));
        hi = max(hi, __shfl_xor(hi, o));
    }
    __shared__ int s_lo, s_hi;
    if (tid == 0) { s_lo = lo; s_hi = hi; }
    __syncthreads();
    lo = s_lo; hi = s_hi;

    float mn = FLT_MAX, mx = -FLT_MAX;
    if (lo < LEN) {
        const float* srow = sig + (size_t)b * LEN;
        const int sl = stripe_of(lo), sh = stripe_of(hi);
        const int e1 = (sl == sh) ? hi : stripe_end(sl);
        for (int l = lo + tid; l <= e1; l += 512) {
            const float x = srow[l]; mn = fminf(mn, x); mx = fmaxf(mx, x);
        }
        if (sh > sl) {
            for (int l = stripe_start(sh) + tid; l <= hi; l += 512) {
                const float x = srow[l]; mn = fminf(mn, x); mx = fmaxf(mx, x);
            }
            const float* cmin_row = cmin_tab + b * BPR * NST;
            const float* cmax_row = cmax_tab + b * BPR * NST;
            for (int s = sl + 1 + tid; s < sh; s += 512) {
                mn = fminf(mn, cmin_row[s]); mx = fmaxf(mx, cmax_row[s]);
            }
        }
    }
    #pragma unroll
    for (int o = 32; o > 0; o >>= 1) {
        mn = fminf(mn, __shfl_xor(mn, o));
        mx = fmaxf(mx, __shfl_xor(mx, o));
    }
    __shared__ float sh_mn[8], sh_mx[8];
    const int w = tid >> 6, lane = tid & 63;
    if (lane == 0) { sh_mn[w] = mn; sh_mx[w] = mx; }
    __syncthreads();
    if (tid == 0) {
        float MN = FLT_MAX, MX = -FLT_MAX;
        #pragma unroll
        for (int i = 0; i < 8; ++i) {
            MN = fminf(MN, sh_mn[i]); MX = fmaxf(MX, sh_mx[i]);
        }
        if (lo >= LEN) { MN = 1e30f; MX = -1e30f; }   // invalid marker: MX < MN
        wmn[which * BATCH + b] = MN;
        wmx[which * BATCH + b] = MX;
    }
}

// ---------- final combine ----------

__global__ void k_combine(const float* __restrict__ bce_blk,
                          const float* __restrict__ sm_blk,
                          const float* __restrict__ wmn,
                          const float* __restrict__ wmx,
                          float* __restrict__ out) {
    const int tid = threadIdx.x;
    float acc_b = 0.0f, acc_s = 0.0f, acc_a = 0.0f;
    for (int i = tid; i < NSEG; i += 256) { acc_b += bce_blk[i]; acc_s += sm_blk[i]; }
    if (tid < BATCH) {
        const float tmn = wmn[tid],          tmx = wmx[tid];
        const float pmn = wmn[BATCH + tid],  pmx = wmx[BATCH + tid];
        if (tmx >= tmn && pmx >= pmn) {      // both windows valid
            const float ta = tmx - tmn;
            const float pa = pmx - pmn;
            const float d  = fabsf(ta - pa);
            acc_a = (ta > 1e-6f) ? d / (ta + 1e-6f) : d;
        }
    }
    #pragma unroll
    for (int o = 32; o > 0; o >>= 1) {
        acc_b += __shfl_xor(acc_b, o);
        acc_s += __shfl_xor(acc_s, o);
        acc_a += __shfl_xor(acc_a, o);
    }
    __shared__ float sb[4], ss[4], sa[4];
    const int w = tid >> 6, lane = tid & 63;
    if (lane == 0) { sb[w] = acc_b; ss[w] = acc_s; sa[w] = acc_a; }
    __syncthreads();
    if (tid == 0) {
        const double B = (double)(sb[0] + sb[1] + sb[2] + sb[3]);
        const double S = (double)(ss[0] + ss[1] + ss[2] + ss[3]);
        const double A = (double)(sa[0] + sa[1] + sa[2] + sa[3]);
        const double bce = B / ((double)BATCH * (double)LEN);
        const double smo = S / ((double)BATCH * (double)(LEN - 1));
        const double amp = A / (double)BATCH;
        out[0] = (float)(1.0 * bce + 0.5 * amp + 0.3 * smo);
    }
}

// ---------- launch ----------

extern "C" void kernel_launch(void* const* d_in, const int* in_sizes, int n_in,
                              void* d_out, int out_size, void* d_ws, size_t ws_size,
                              hipStream_t stream) {
    const float* signals = (const float*)d_in[0];   // (B, 1, L)
    const float* preds   = (const float*)d_in[1];   // (B, L, 1)
    const float* targs   = (const float*)d_in[2];   // (B, L, 1)
    float* out = (float*)d_out;
    WS w = ws_layout(d_ws);

    dim3 gm(BPR, BATCH);   // 512 blocks x 16 waves = 8192 waves = 1 generation
    k_main<<<gm, T, 0, stream>>>(signals, preds, targs,
                                 w.lt_tab, w.ht_tab, w.lp_tab, w.hp_tab,
                                 w.bce_blk, w.sm_blk, w.cmin, w.cmax);

    dim3 gr(BATCH, 2);
    k_rows<<<gr, 512, 0, stream>>>(signals,
                                   w.lt_tab, w.ht_tab, w.lp_tab, w.hp_tab,
                                   w.cmin, w.cmax, w.wmn, w.wmx);

    k_combine<<<1, 256, 0, stream>>>(w.bce_blk, w.sm_blk, w.wmn, w.wmx, out);
}